// Round 6
// baseline (159.450 us; speedup 1.0000x reference)
//
#include <hip/hip_runtime.h>
#include <hip/hip_bf16.h>

#define EMBED 1024
#define WINDOW 512
#define NROWS 16384  // 4 * 4096

typedef __attribute__((ext_vector_type(4))) float f32x4;
typedef __bf16 bf16x8 __attribute__((ext_vector_type(8)));

#define GLDS(g, l)                                                        \
  __builtin_amdgcn_global_load_lds(                                       \
      (const __attribute__((address_space(1))) void*)(const void*)(g),    \
      (__attribute__((address_space(3))) void*)(void*)(l), 16, 0, 0)

// ---------------- prep: fp32 -> bf16 cast, 8 elems/thread ----------------
__global__ __launch_bounds__(256) void cast_bf16_kernel(
    const float* __restrict__ in, __bf16* __restrict__ out, int n8) {
  int i = blockIdx.x * blockDim.x + threadIdx.x;
  if (i >= n8) return;
  const f32x4* p = (const f32x4*)(in + (size_t)i * 8);
  f32x4 a = p[0], b = p[1];
  bf16x8 o = {(__bf16)a[0], (__bf16)a[1], (__bf16)a[2], (__bf16)a[3],
              (__bf16)b[0], (__bf16)b[1], (__bf16)b[2], (__bf16)b[3]};
  *(bf16x8*)(out + (size_t)i * 8) = o;
}

// ---------------- prep: MB [512][1024] fp32 -> MB^T [1024][512] bf16 ------
__global__ __launch_bounds__(256) void transpose_mb_kernel(
    const float* __restrict__ mb, __bf16* __restrict__ mbt) {
  int idx = blockIdx.x * blockDim.x + threadIdx.x;  // over 512*1024
  int w = idx >> 10, d = idx & 1023;
  mbt[(size_t)d * WINDOW + w] = (__bf16)mb[idx];
}

// ---------------- softmax in-place on S1 rows (512 wide) -----------------
__global__ __launch_bounds__(256) void softmax_kernel(__bf16* __restrict__ s1) {
  const int row = blockIdx.x * 4 + (threadIdx.x >> 6);
  const int lane = threadIdx.x & 63;
  __bf16* p = s1 + (size_t)row * WINDOW + lane * 8;
  bf16x8 v = *(const bf16x8*)p;
  float f[8];
  float mx = -1e30f;
#pragma unroll
  for (int j = 0; j < 8; ++j) {
    f[j] = (float)v[j] * 0.03125f;  // 1/sqrt(1024)
    mx = fmaxf(mx, f[j]);
  }
#pragma unroll
  for (int off = 1; off < 64; off <<= 1) mx = fmaxf(mx, __shfl_xor(mx, off));
  float s = 0.f;
#pragma unroll
  for (int j = 0; j < 8; ++j) {
    f[j] = __expf(f[j] - mx);
    s += f[j];
  }
#pragma unroll
  for (int off = 1; off < 64; off <<= 1) s += __shfl_xor(s, off);
  const float inv = 1.0f / s;
  bf16x8 o;
#pragma unroll
  for (int j = 0; j < 8; ++j) o[j] = (__bf16)(f[j] * inv);
  *(bf16x8*)p = o;
}

// ---------------- scores kernel (R5 structure, unchanged) ----------------
#define SLOADFRAGS(cb, kk)                                                    \
  {                                                                           \
    const __bf16* As_ = &ldsA[cb][(warp_m * 64 + fr) * 64];                   \
    const __bf16* Bs_ = &ldsB[cb][(warp_n * 64 + fr) * 64];                   \
    const int pg_ = (((kk)*4 + fq) ^ (fr & 7)) * 8;                           \
    _Pragma("unroll") for (int m = 0; m < 4; ++m)                             \
        af[m] = *(const bf16x8*)(As_ + m * 16 * 64 + pg_);                    \
    _Pragma("unroll") for (int n = 0; n < 4; ++n)                             \
        bfv[n] = *(const bf16x8*)(Bs_ + n * 16 * 64 + pg_);                   \
  }

#define SMFMA16(ACC)                                                          \
  {                                                                           \
    __builtin_amdgcn_s_barrier();                                             \
    asm volatile("s_waitcnt lgkmcnt(0)" ::: "memory");                        \
    __builtin_amdgcn_s_setprio(1);                                            \
    _Pragma("unroll") for (int m = 0; m < 4; ++m)                             \
        _Pragma("unroll") for (int n = 0; n < 4; ++n)                         \
            ACC[m][n] = __builtin_amdgcn_mfma_f32_16x16x32_bf16(              \
                af[m], bfv[n], ACC[m][n], 0, 0, 0);                           \
    __builtin_amdgcn_s_setprio(0);                                            \
    __builtin_amdgcn_s_barrier();                                             \
  }

__global__ __launch_bounds__(512, 2) void gemm_scores_kernel(
    const __bf16* __restrict__ xb, const __bf16* __restrict__ mbb,
    __bf16* __restrict__ s1) {
  __shared__ __align__(16) __bf16 ldsA[3][256 * 64];
  __shared__ __align__(16) __bf16 ldsB[3][128 * 64];
  const int tid = threadIdx.x;
  const int lane = tid & 63;
  const int wave = tid >> 6;
  const int bid = blockIdx.x;            // 256 blocks
  const int xcd = bid & 7;
  const int idx = bid >> 3;              // 0..31
  const int bm = xcd * 8 + (idx & 7);    // 0..63
  const int bn = idx >> 3;               // 0..3
  const int row0 = bm * 256;
  const int col0 = bn * 128;
  const int warp_m = wave >> 1;
  const int warp_n = wave & 1;
  const int srow = lane >> 3;
  const int sgc = (lane & 7) ^ srow;
  const int wv32 = wave * 32;
  const int wv16 = wave * 16;
  const int fr = lane & 15;
  const int fq = lane >> 4;

  const __bf16* aS = xb + (size_t)(row0 + wv32 + srow) * EMBED + sgc * 8;
  const __bf16* bS = mbb + (size_t)(col0 + wv16 + srow) * EMBED + sgc * 8;

#define STAGE_S1(vt, buf)                                                     \
  {                                                                           \
    const int k0_ = (vt)*64;                                                  \
    _Pragma("unroll") for (int c = 0; c < 2; ++c)                             \
        GLDS(aS + (size_t)c * 8 * EMBED + k0_, &ldsA[buf][(wv32 + c * 8) * 64]); \
    GLDS(bS + k0_, &ldsB[buf][wv16 * 64]);                                    \
  }
#define STAGE_S2(vt, buf)                                                     \
  {                                                                           \
    const int k0_ = (vt)*64;                                                  \
    _Pragma("unroll") for (int c = 2; c < 4; ++c)                             \
        GLDS(aS + (size_t)c * 8 * EMBED + k0_, &ldsA[buf][(wv32 + c * 8) * 64]); \
    GLDS(bS + (size_t)8 * EMBED + k0_, &ldsB[buf][(wv16 + 8) * 64]);          \
  }

  f32x4 acc[4][4];
#pragma unroll
  for (int m = 0; m < 4; ++m)
#pragma unroll
    for (int n = 0; n < 4; ++n) acc[m][n] = (f32x4){0.f, 0.f, 0.f, 0.f};
  bf16x8 af[4], bfv[4];

  STAGE_S1(0, 0); STAGE_S2(0, 0);
  STAGE_S1(1, 1); STAGE_S2(1, 1);
  asm volatile("s_waitcnt vmcnt(6)" ::: "memory");
  __builtin_amdgcn_s_barrier();

  const int NT = 16;
  for (int vt = 0; vt < NT; ++vt) {
    const int cb = vt % 3;
    const int nb = (vt + 2) % 3;
    SLOADFRAGS(cb, 0);
    if (vt + 2 < NT) STAGE_S1(vt + 2, nb);
    SMFMA16(acc);
    SLOADFRAGS(cb, 1);
    if (vt + 2 < NT) STAGE_S2(vt + 2, nb);
    if (vt < NT - 2) {
      asm volatile("s_waitcnt vmcnt(6)" ::: "memory");
    } else if (vt == NT - 2) {
      asm volatile("s_waitcnt vmcnt(0)" ::: "memory");
    }
    SMFMA16(acc);
  }
#undef STAGE_S1
#undef STAGE_S2

#pragma unroll
  for (int n = 0; n < 4; ++n) {
    const int col = col0 + warp_n * 64 + n * 16 + fr;
#pragma unroll
    for (int m = 0; m < 4; ++m)
#pragma unroll
      for (int j = 0; j < 4; ++j) {
        const int row = row0 + warp_m * 64 + m * 16 + fq * 4 + j;
        s1[(size_t)row * WINDOW + col] = (__bf16)acc[m][n][j];
      }
  }
}

// ============== m201-geometry GEMM: BM=BN=256, wave tile 128x64 ==========
// 8 waves (2M x 4N), BK=32, 4-slot LDS ring (3-tile lookahead), per tile:
//   ph0: read A m0..3 (4 ds) + B n0..3 (4 ds), stage A(t+3), bar, 16 MFMA
//   ph1: read A m4..7 (4 ds, B reused in regs), stage B(t+3),
//        counted vmcnt (8 -> 4 -> 0 tail), bar, 16 MFMA
// Swizzle: read granule fq ^ ((fr>>1)&3); source pre-swizzle
// (lane&3)^((lane>>3)&3) — involution, stride-1 bank profile.
// EPI: 0 = write acc->rbb bf16 ; 1 = blend(read rbb bf16) -> out f32
//      2 = write acc->out f32  ; 3 = blend(read out f32)  -> out f32
template <int NT, int LDA_, int LDB_, int EPI>
__global__ __launch_bounds__(512, 2) void gemm_mt_kernel(
    const __bf16* __restrict__ A, const __bf16* __restrict__ B,
    const float* __restrict__ gb, __bf16* __restrict__ rbb,
    float* __restrict__ out) {
  __shared__ __align__(16) __bf16 ldsA[4][256 * 32];
  __shared__ __align__(16) __bf16 ldsB[4][256 * 32];
  const int tid = threadIdx.x, lane = tid & 63, wave = tid >> 6;
  const int bid = blockIdx.x;                  // 256 blocks
  const int bm = (bid & 7) * 8 + ((bid >> 3) & 7);  // 0..63
  const int bn = bid >> 6;                     // 0..3
  const int row0 = bm * 256, col0 = bn * 256;
  const int warp_m = wave >> 2;                // 0..1 -> 128 rows
  const int warp_n = wave & 3;                 // 0..3 -> 64 cols
  const int fr = lane & 15, fq = lane >> 4;

  // staging: per glds, 16 rows x 4 granules; lane -> row lane>>2, gran lane&3
  const int lrow = lane >> 2;
  const int lsg = (lane & 3) ^ ((lane >> 3) & 3);
  const __bf16* aSrc = A + (size_t)(row0 + wave * 32 + lrow) * LDA_ + lsg * 8;
  const __bf16* bSrc = B + (size_t)(col0 + wave * 32 + lrow) * LDB_ + lsg * 8;

#define STG_A(t, c)                                                           \
  GLDS(aSrc + (size_t)(c) * 16 * LDA_ + (t) * 32,                             \
       &ldsA[(t) & 3][(wave * 32 + (c) * 16) * 32])
#define STG_B(t, c)                                                           \
  GLDS(bSrc + (size_t)(c) * 16 * LDB_ + (t) * 32,                             \
       &ldsB[(t) & 3][(wave * 32 + (c) * 16) * 32])

  f32x4 acc[8][4];
#pragma unroll
  for (int m = 0; m < 8; ++m)
#pragma unroll
    for (int n = 0; n < 4; ++n) acc[m][n] = (f32x4){0.f, 0.f, 0.f, 0.f};
  bf16x8 af[4], bfv[4];
  const int gA = (fq ^ ((fr >> 1) & 3)) * 8;  // swizzled granule (elems)

  // prologue: stage tiles 0,1,2; wait tile-0 (leave 8 in flight)
  STG_A(0, 0); STG_A(0, 1); STG_B(0, 0); STG_B(0, 1);
  STG_A(1, 0); STG_A(1, 1); STG_B(1, 0); STG_B(1, 1);
  STG_A(2, 0); STG_A(2, 1); STG_B(2, 0); STG_B(2, 1);
  asm volatile("s_waitcnt vmcnt(8)" ::: "memory");
  __builtin_amdgcn_s_barrier();

  for (int t = 0; t < NT; ++t) {
    const int s = t & 3;
    const __bf16* As = &ldsA[s][(warp_m * 128 + fr) * 32 + gA];
    const __bf16* Bs = &ldsB[s][(warp_n * 64 + fr) * 32 + gA];
    // ---- ph0: m0..3 x n0..3 ----
#pragma unroll
    for (int m = 0; m < 4; ++m) af[m] = *(const bf16x8*)(As + m * 16 * 32);
#pragma unroll
    for (int n = 0; n < 4; ++n) bfv[n] = *(const bf16x8*)(Bs + n * 16 * 32);
    if (t + 3 < NT) { STG_A(t + 3, 0); STG_A(t + 3, 1); }
    __builtin_amdgcn_s_barrier();
    asm volatile("s_waitcnt lgkmcnt(0)" ::: "memory");
    __builtin_amdgcn_s_setprio(1);
#pragma unroll
    for (int m = 0; m < 4; ++m)
#pragma unroll
      for (int n = 0; n < 4; ++n)
        acc[m][n] = __builtin_amdgcn_mfma_f32_16x16x32_bf16(af[m], bfv[n],
                                                            acc[m][n], 0, 0, 0);
    __builtin_amdgcn_s_setprio(0);
    __builtin_amdgcn_s_barrier();
    // ---- ph1: m4..7 x n0..3 (B reused) ----
#pragma unroll
    for (int m = 0; m < 4; ++m)
      af[m] = *(const bf16x8*)(As + (64 + m * 16) * 32);
    if (t + 3 < NT) { STG_B(t + 3, 0); STG_B(t + 3, 1); }
    if (t + 1 < NT) {
      if (t + 3 < NT) {
        asm volatile("s_waitcnt vmcnt(8)" ::: "memory");
      } else if (t + 2 < NT) {
        asm volatile("s_waitcnt vmcnt(4)" ::: "memory");
      } else {
        asm volatile("s_waitcnt vmcnt(0)" ::: "memory");
      }
    }
    __builtin_amdgcn_s_barrier();
    asm volatile("s_waitcnt lgkmcnt(0)" ::: "memory");
    __builtin_amdgcn_s_setprio(1);
#pragma unroll
    for (int m = 0; m < 4; ++m)
#pragma unroll
      for (int n = 0; n < 4; ++n)
        acc[4 + m][n] = __builtin_amdgcn_mfma_f32_16x16x32_bf16(
            af[m], bfv[n], acc[4 + m][n], 0, 0, 0);
    __builtin_amdgcn_s_setprio(0);
    __builtin_amdgcn_s_barrier();
  }
#undef STG_A
#undef STG_B

  // epilogue
#pragma unroll
  for (int n = 0; n < 4; ++n) {
    const int col = col0 + warp_n * 64 + n * 16 + fr;
    float bias = 0.f;
    if (EPI == 1 || EPI == 3) bias = gb[col];
#pragma unroll
    for (int m = 0; m < 8; ++m) {
#pragma unroll
      for (int j = 0; j < 4; ++j) {
        const int row = row0 + warp_m * 128 + m * 16 + fq * 4 + j;
        const size_t o = (size_t)row * EMBED + col;
        if (EPI == 0) {
          rbb[o] = (__bf16)acc[m][n][j];
        } else if (EPI == 2) {
          out[o] = acc[m][n][j];
        } else {
          const float g = 1.0f / (1.0f + __expf(-(acc[m][n][j] + bias)));
          const float xv = (float)A[(size_t)row * EMBED + col];
          const float rv = (EPI == 1) ? (float)rbb[o] : out[o];
          out[o] = g * xv + (1.0f - g) * rv;
        }
      }
    }
  }
}

extern "C" void kernel_launch(void* const* d_in, const int* in_sizes, int n_in,
                              void* d_out, int out_size, void* d_ws,
                              size_t ws_size, hipStream_t stream) {
  const float* x = (const float*)d_in[0];
  const float* mb = (const float*)d_in[1];
  const float* gw = (const float*)d_in[2];
  const float* gb = (const float*)d_in[3];
  float* out = (float*)d_out;

  char* ws = (char*)d_ws;
  __bf16* xb = (__bf16*)(ws);                   // 16384*1024*2 = 33,554,432
  __bf16* mbb = (__bf16*)(ws + 33554432);       // 512*1024*2  =  1,048,576
  __bf16* mbt = (__bf16*)(ws + 34603008);       // 1024*512*2  =  1,048,576
  __bf16* gwb = (__bf16*)(ws + 35651584);       // 1024*1024*2 =  2,097,152
  __bf16* s1 = (__bf16*)(ws + 37748736);        // 16384*512*2 = 16,777,216
  __bf16* rbb = (__bf16*)(ws + 54525952);       // 16384*1024*2 = 33,554,432
  // total (fast path) = 88,080,384 bytes
  const bool ws_big = ws_size >= 88080384ull;

  cast_bf16_kernel<<<8192, 256, 0, stream>>>(x, xb, 2097152);
  cast_bf16_kernel<<<256, 256, 0, stream>>>(mb, mbb, 65536);
  cast_bf16_kernel<<<512, 256, 0, stream>>>(gw, gwb, 131072);
  transpose_mb_kernel<<<2048, 256, 0, stream>>>(mb, mbt);
  gemm_scores_kernel<<<256, 512, 0, stream>>>(xb, mbb, s1);
  softmax_kernel<<<4096, 256, 0, stream>>>(s1);
  if (ws_big) {
    // retrieved = softmax(S1) @ MB -> bf16 ws
    gemm_mt_kernel<16, WINDOW, WINDOW, 0><<<256, 512, 0, stream>>>(
        s1, mbt, gb, rbb, out);
    // gate + blend
    gemm_mt_kernel<32, EMBED, EMBED, 1><<<256, 512, 0, stream>>>(
        xb, gwb, gb, rbb, out);
  } else {
    gemm_mt_kernel<16, WINDOW, WINDOW, 2><<<256, 512, 0, stream>>>(
        s1, mbt, gb, nullptr, out);
    gemm_mt_kernel<32, EMBED, EMBED, 3><<<256, 512, 0, stream>>>(
        xb, gwb, gb, nullptr, out);
  }
}